// Round 1
// baseline (578.241 us; speedup 1.0000x reference)
//
#include <hip/hip_runtime.h>
#include <hip/hip_bf16.h>

// DenseBlockEnd: out = relu(mask * (node + b1*sum_l A_l@Win_l + b2*BO@Wout))
// B=512, M=256, F=256, L_IN=2, L_OUT=1.
// Fused as C[131072,256] = X[131072,768] @ Wt^T + node, row-masked ReLU.
// Wt (bf16, beta-folded, SWIZZLED tile-major layout) staged in d_ws by prep kernel.
//
// Pipeline (T14+T4): X(k+1) global->reg issued before MFMA(k); W(k) staged via
// global_load_lds DMA; raw s_barrier + counted vmcnt(4) so prefetch survives
// barriers. LDS XOR-swizzle (byte ^= (row&7)<<4) -> 2-way (free) b128 reads.

#define BATCH  512
#define MAXA   256
#define FDIM   256
#define KTOT   768
#define TILE_M 128
#define BK     64
#define NKT    12         // 768/64 K-steps

typedef __attribute__((ext_vector_type(8))) short  short8;   // 8 bf16 (MFMA A/B frag)
typedef __attribute__((ext_vector_type(4))) float  fx4;      // MFMA C/D frag
typedef const __attribute__((address_space(1))) unsigned int GASU;
typedef __attribute__((address_space(3))) unsigned int LASU;

__device__ __forceinline__ unsigned short f2bf(float x) {
  // round-to-nearest-even fp32 -> bf16 (inputs are finite normals)
  unsigned int u = __builtin_bit_cast(unsigned int, x);
  u += 0x7fffu + ((u >> 16) & 1u);
  return (unsigned short)(u >> 16);
}

__device__ __forceinline__ short8 cvt8(fx4 a, fx4 b) {
  short8 r;
  r[0] = (short)f2bf(a[0]); r[1] = (short)f2bf(a[1]);
  r[2] = (short)f2bf(a[2]); r[3] = (short)f2bf(a[3]);
  r[4] = (short)f2bf(b[0]); r[5] = (short)f2bf(b[1]);
  r[6] = (short)f2bf(b[2]); r[7] = (short)f2bf(b[3]);
  return r;
}

// Wt layout: tile-major, 12 tiles of 16384 shorts (rows n=0..255 x k'=0..63),
// short index within tile = ((n<<6)|k') ^ ((n&7)<<3)  [= byte (n*128+k'*2) ^ ((n&7)<<4)].
// This is exactly the LDS image fused_main DMA-copies per K-step (rule #21:
// linear global_load_lds dest + pre-swizzled source + swizzled ds_read).
__global__ void prep_weights(const float* __restrict__ Win,
                             const float* __restrict__ Wout,
                             const float* __restrict__ b1,
                             const float* __restrict__ b2,
                             unsigned short* __restrict__ Wt) {
  int id = blockIdx.x * 256 + threadIdx.x;   // 0 .. 196607, id = n*768 + k
  int n = id / KTOT;
  int k = id - n * KTOT;
  float beta, w;
  if (k < 512) { beta = b1[0]; w = Win[k * FDIM + n]; }
  else         { beta = b2[0]; w = Wout[(k - 512) * FDIM + n]; }
  int tt = k >> 6;
  int kl = k & 63;
  int dst = (tt << 14) + (((n << 6) | kl) ^ ((n & 7) << 3));
  Wt[dst] = f2bf(beta * w);
}

__launch_bounds__(512, 4)
__global__ void fused_main(const float* __restrict__ node,
                           const float* __restrict__ acts,   // [2][131072][256]
                           const float* __restrict__ bouts,  // [1][131072][256]
                           const int*   __restrict__ mol_slice,
                           const unsigned short* __restrict__ Wt,
                           float* __restrict__ out) {
  const int tile  = blockIdx.x;        // 1024 tiles of 128 rows
  const int bmol  = tile >> 1;
  const int m0    = (tile & 1) << 7;
  const int slice = mol_slice[bmol];
  const int t     = threadIdx.x;
  const long rowBase = (long)tile * TILE_M;

  if (slice <= m0) {
    // whole tile masked: zero-fill 128x256 output, skip all reads/compute
    fx4 z = {0.f, 0.f, 0.f, 0.f};
    fx4* o4 = (fx4*)(out + rowBase * FDIM);
#pragma unroll
    for (int i = 0; i < 16; ++i) o4[i * 512 + t] = z;
    return;
  }

  __shared__ unsigned short Xs[TILE_M * BK];   // 16384 B, XOR-swizzled
  __shared__ unsigned short Ws[FDIM * BK];     // 32768 B, XOR-swizzled (DMA image)

  const int lane = t & 63;
  const int wv   = t >> 6;            // 8 waves
  const int wm   = (wv >> 2) << 6;    // wave row offset: 0 / 64
  const int wn   = (wv & 3) << 6;     // wave col offset: 0/64/128/192

  fx4 acc[4][4];
#pragma unroll
  for (int i = 0; i < 4; ++i)
#pragma unroll
    for (int j = 0; j < 4; ++j) acc[i][j] = (fx4){0.f, 0.f, 0.f, 0.f};

  // X staging map: 4 threads/row, 16 fp32 each (64 B contiguous per thread)
  const int xrow = t >> 2;
  const int xc   = (t & 3) << 4;                 // fp32 element offset in [0,64)
  const bool waveX = (m0 + (wv << 4)) < slice;   // wave's 16 staging rows: any active?
  const bool waveC = (m0 + wm) < slice;          // wave's 64 compute rows: any active?
  const long xgbase = (rowBase + xrow) * FDIM + xc;
  const float* acts2 = acts + 33554432;

  // prologue: issue X(0) into regs
  fx4 v0, v1, v2, v3;
  if (waveX) {
    const fx4* g = (const fx4*)(acts + xgbase);
    v0 = g[0]; v1 = g[1]; v2 = g[2]; v3 = g[3];
  }

  const char* WtB = (const char*)Wt;
  char* lW = (char*)Ws + (wv << 10);

  for (int kt = 0; kt < NKT; ++kt) {
    // 1) issue Ws(kt) DMA: 4x global_load_lds dwordx4 per thread (32 KB tile)
    {
      const char* gW = WtB + (kt << 15) + (wv << 10) + (lane << 4);
#pragma unroll
      for (int r = 0; r < 4; ++r)
        __builtin_amdgcn_global_load_lds((GASU*)(const void*)(gW + (r << 13)),
                                         (LASU*)(void*)(lW + (r << 13)), 16, 0, 0);
    }

    // 2) X(kt) regs have arrived (issued last iter, before the 4 glds): vmcnt(4)
    if (waveX) {
      asm volatile("s_waitcnt vmcnt(4)" ::: "memory");
      short8 pa = cvt8(v0, v1);
      short8 pb = cvt8(v2, v3);
      const int ba = ((xrow << 7) + (xc << 1)) ^ ((xrow & 7) << 4);
      *(short8*)((char*)Xs + ba)        = pa;
      *(short8*)((char*)Xs + (ba ^ 16)) = pb;
    }

    // 3) issue X(kt+1) -> regs (in flight across barrier + MFMA phase)
    const bool pre = waveX && (kt != NKT - 1);
    if (pre) {
      const int kkn = (kt + 1) << 6;
      const float* srcn = (kkn < 256) ? acts : ((kkn < 512) ? acts2 : bouts);
      const fx4* g = (const fx4*)(srcn + xgbase + (kkn & 255));
      v0 = g[0]; v1 = g[1]; v2 = g[2]; v3 = g[3];
    }

    // 4) wait Ws(kt) landed (X(kt+1) 4 loads stay in flight), LDS writes visible
    if (pre) asm volatile("s_waitcnt vmcnt(4)" ::: "memory");
    else     asm volatile("s_waitcnt vmcnt(0)" ::: "memory");
    asm volatile("s_waitcnt lgkmcnt(0)" ::: "memory");
    __builtin_amdgcn_s_barrier();

    // 5) MFMA phase (skip if all 64 of this wave's output rows are masked)
    if (waveC) {
#pragma unroll
      for (int s = 0; s < 2; ++s) {
        const int ko2 = ((s << 5) + ((lane >> 4) << 3)) << 1;   // byte col, 16B-aligned
        short8 af[4], bfr[4];
#pragma unroll
        for (int i = 0; i < 4; ++i) {
          const int m = wm + (i << 4) + (lane & 15);
          af[i] = *(const short8*)((const char*)Xs + (((m << 7) + ko2) ^ ((m & 7) << 4)));
        }
#pragma unroll
        for (int j = 0; j < 4; ++j) {
          const int n = wn + (j << 4) + (lane & 15);
          bfr[j] = *(const short8*)((const char*)Ws + (((n << 7) + ko2) ^ ((n & 7) << 4)));
        }
#pragma unroll
        for (int i = 0; i < 4; ++i)
#pragma unroll
          for (int j = 0; j < 4; ++j)
            acc[i][j] = __builtin_amdgcn_mfma_f32_16x16x32_bf16(af[i], bfr[j], acc[i][j], 0, 0, 0);
      }
    }
    __builtin_amdgcn_s_barrier();   // protect Xs/Ws overwrite next iter
  }

  // epilogue: C/D layout col=lane&15, row=(lane>>4)*4+reg (m89-verified)
  const int cq = lane >> 4;
  const int cl = lane & 15;
#pragma unroll
  for (int i = 0; i < 4; ++i) {
    const int rb = wm + (i << 4) + (cq << 2);
#pragma unroll
    for (int r = 0; r < 4; ++r) {
      const int lrow = rb + r;
      const int m = m0 + lrow;
      const long gro = (rowBase + lrow) * FDIM;
      const bool act = m < slice;
#pragma unroll
      for (int j = 0; j < 4; ++j) {
        const int col = wn + (j << 4) + cl;
        float v = 0.f;
        if (act) {
          v = node[gro + col] + acc[i][j][r];
          v = fmaxf(v, 0.f);
        }
        out[gro + col] = v;
      }
    }
  }
}

extern "C" void kernel_launch(void* const* d_in, const int* in_sizes, int n_in,
                              void* d_out, int out_size, void* d_ws, size_t ws_size,
                              hipStream_t stream) {
  const float* node  = (const float*)d_in[0];
  const float* acts  = (const float*)d_in[1];
  const float* bouts = (const float*)d_in[2];
  const int*   mslc  = (const int*)d_in[3];
  const float* Win   = (const float*)d_in[4];
  const float* Wout  = (const float*)d_in[5];
  const float* b1    = (const float*)d_in[6];
  const float* b2    = (const float*)d_in[7];
  float* out = (float*)d_out;
  unsigned short* Wt = (unsigned short*)d_ws;   // 768*256*2 = 393216 B

  prep_weights<<<dim3(768), dim3(256), 0, stream>>>(Win, Wout, b1, b2, Wt);
  fused_main<<<dim3(1024), dim3(512), 0, stream>>>(node, acts, bouts, mslc, Wt, out);
}